// Round 1
// baseline (618.745 us; speedup 1.0000x reference)
//
#include <hip/hip_runtime.h>
#include <hip/hip_bf16.h>
#include <cstdint>
#include <cstddef>

#define BN_EPS 1e-3f

// ---------------------------------------------------------------------------
// GEMM: out-tile 64 rows x 128 cols, A [N x K] (lda), B [K x 128], fused epilogue.
// MODE 0: h = relu(A@B + bias)                      (embedding)
// MODE 1: h += relu((A@B)/deg * bn_scale + (bc*bn_scale + beta))   (conv layer)
// ---------------------------------------------------------------------------
template<int MODE>
__global__ __launch_bounds__(256) void gemm128(
    const float* __restrict__ A, int lda, int K, int N,
    const float* __restrict__ B,
    const float* __restrict__ bias,
    const float* __restrict__ deg,
    const float* __restrict__ bc,
    const float* __restrict__ gamma,
    const float* __restrict__ beta,
    float* __restrict__ h)
{
  __shared__ float As[64][33];   // +1 pad: conflict-free column reads
  __shared__ float Bs[32][128];
  const int tid = threadIdx.x;
  const int tx = tid & 31;       // 32 col-quads (4 cols each)
  const int ty = tid >> 5;       // 8 row-octets (8 rows each)
  const int m0 = blockIdx.x * 64;

  float acc[8][4];
  #pragma unroll
  for (int r = 0; r < 8; r++)
    #pragma unroll
    for (int q = 0; q < 4; q++) acc[r][q] = 0.f;

  for (int k0 = 0; k0 < K; k0 += 32) {
    // stage A: 64 x 32
    #pragma unroll
    for (int i = 0; i < 2; i++) {
      int f  = tid + i * 256;          // 0..511 quads
      int r  = f >> 3;
      int kq = (f & 7) * 4;
      float4 v = make_float4(0.f, 0.f, 0.f, 0.f);
      int gr = m0 + r;
      if (gr < N) {
        if (k0 + kq + 4 <= K) {
          v = *reinterpret_cast<const float4*>(&A[(size_t)gr * lda + k0 + kq]);
        } else {
          float t0 = (k0 + kq + 0 < K) ? A[(size_t)gr * lda + k0 + kq + 0] : 0.f;
          float t1 = (k0 + kq + 1 < K) ? A[(size_t)gr * lda + k0 + kq + 1] : 0.f;
          float t2 = (k0 + kq + 2 < K) ? A[(size_t)gr * lda + k0 + kq + 2] : 0.f;
          float t3 = (k0 + kq + 3 < K) ? A[(size_t)gr * lda + k0 + kq + 3] : 0.f;
          v = make_float4(t0, t1, t2, t3);
        }
      }
      As[r][kq + 0] = v.x; As[r][kq + 1] = v.y;
      As[r][kq + 2] = v.z; As[r][kq + 3] = v.w;
    }
    // stage B: 32 x 128
    #pragma unroll
    for (int i = 0; i < 4; i++) {
      int f4   = tid + i * 256;        // float4 index 0..1023
      int flat = f4 * 4;
      int k = flat >> 7;
      int j = flat & 127;
      float4 v = make_float4(0.f, 0.f, 0.f, 0.f);
      if (k0 + k < K)
        v = *reinterpret_cast<const float4*>(&B[(size_t)(k0 + k) * 128 + j]);
      *reinterpret_cast<float4*>(&Bs[k][j]) = v;
    }
    __syncthreads();
    #pragma unroll
    for (int k = 0; k < 32; k++) {
      float4 b = *reinterpret_cast<const float4*>(&Bs[k][tx * 4]);
      #pragma unroll
      for (int r = 0; r < 8; r++) {
        float a = As[ty * 8 + r][k];
        acc[r][0] += a * b.x; acc[r][1] += a * b.y;
        acc[r][2] += a * b.z; acc[r][3] += a * b.w;
      }
    }
    __syncthreads();
  }

  const int c = tx * 4;
  if (MODE == 0) {
    float4 bb = *reinterpret_cast<const float4*>(&bias[c]);
    #pragma unroll
    for (int r = 0; r < 8; r++) {
      int gr = m0 + ty * 8 + r;
      if (gr < N) {
        float4 o;
        o.x = fmaxf(acc[r][0] + bb.x, 0.f);
        o.y = fmaxf(acc[r][1] + bb.y, 0.f);
        o.z = fmaxf(acc[r][2] + bb.z, 0.f);
        o.w = fmaxf(acc[r][3] + bb.w, 0.f);
        *reinterpret_cast<float4*>(&h[(size_t)gr * 128 + c]) = o;
      }
    }
  } else {
    const float rs = rsqrtf(1.f + BN_EPS);
    float4 ga  = *reinterpret_cast<const float4*>(&gamma[c]);
    float4 bcv = *reinterpret_cast<const float4*>(&bc[c]);
    float4 be  = *reinterpret_cast<const float4*>(&beta[c]);
    float4 sc  = make_float4(ga.x * rs, ga.y * rs, ga.z * rs, ga.w * rs);
    float4 ofs = make_float4(bcv.x * sc.x + be.x, bcv.y * sc.y + be.y,
                             bcv.z * sc.z + be.z, bcv.w * sc.w + be.w);
    #pragma unroll
    for (int r = 0; r < 8; r++) {
      int gr = m0 + ty * 8 + r;
      if (gr < N) {
        float id = 1.f / deg[gr];
        float4 hv = *reinterpret_cast<const float4*>(&h[(size_t)gr * 128 + c]);
        hv.x += fmaxf(acc[r][0] * sc.x * id + ofs.x, 0.f);
        hv.y += fmaxf(acc[r][1] * sc.y * id + ofs.y, 0.f);
        hv.z += fmaxf(acc[r][2] * sc.z * id + ofs.z, 0.f);
        hv.w += fmaxf(acc[r][3] * sc.w * id + ofs.w, 0.f);
        *reinterpret_cast<float4*>(&h[(size_t)gr * 128 + c]) = hv;
      }
    }
  }
}

// ---------------------------------------------------------------------------
// CSR build
// ---------------------------------------------------------------------------
__global__ void hist_kernel(const int* __restrict__ rows, int* __restrict__ cnt, int E) {
  int e = blockIdx.x * 256 + threadIdx.x;
  if (e < E) atomicAdd(&cnt[rows[e]], 1);
}

__global__ __launch_bounds__(1024) void scan_kernel(const int* __restrict__ cnt,
                                                    int* __restrict__ row_ptr, int N) {
  __shared__ int wsum[16];
  __shared__ int woff[16];
  __shared__ int carry;
  const int tid  = threadIdx.x;
  const int lane = tid & 63, wid = tid >> 6;
  if (tid == 0) { carry = 0; row_ptr[0] = 0; }
  __syncthreads();
  for (int base = 0; base < N; base += 8192) {
    int c = carry;
    int v[8]; int s = 0;
    #pragma unroll
    for (int i = 0; i < 8; i++) {
      int idx = base + tid * 8 + i;
      v[i] = (idx < N) ? cnt[idx] : 0;
      s += v[i];
    }
    int sc = s;
    #pragma unroll
    for (int o = 1; o < 64; o <<= 1) {
      int u = __shfl_up(sc, o);
      if (lane >= o) sc += u;
    }
    if (lane == 63) wsum[wid] = sc;
    __syncthreads();
    if (tid == 0) {
      int run = 0;
      for (int i = 0; i < 16; i++) { int t = wsum[i]; woff[i] = run; run += t; }
      carry = c + run;
    }
    __syncthreads();
    int run = c + woff[wid] + (sc - s);
    #pragma unroll
    for (int i = 0; i < 8; i++) {
      int idx = base + tid * 8 + i;
      run += v[i];
      if (idx < N) row_ptr[idx + 1] = run;
    }
  }
}

__global__ void fill_kernel(const int* __restrict__ rows, const int* __restrict__ cols,
                            const int* __restrict__ row_ptr, int* __restrict__ fill_cnt,
                            int* __restrict__ csr_col, int* __restrict__ csr_eid, int E) {
  int e = blockIdx.x * 256 + threadIdx.x;
  if (e < E) {
    int r   = rows[e];
    int pos = atomicAdd(&fill_cnt[r], 1);
    int at  = row_ptr[r] + pos;
    csr_col[at] = cols[e];
    csr_eid[at] = e;
  }
}

// ---------------------------------------------------------------------------
// T = segment_sum(edge_attr) into ST[:,128:192]; deg from CSR. One wave per row.
// ---------------------------------------------------------------------------
__global__ __launch_bounds__(256) void build_T_deg(
    const float* __restrict__ eattr, const int* __restrict__ row_ptr,
    const int* __restrict__ csr_eid, float* __restrict__ ST,
    float* __restrict__ deg, int N)
{
  int r = blockIdx.x * 4 + (threadIdx.x >> 6);
  if (r >= N) return;
  int lane = threadIdx.x & 63;
  int s = row_ptr[r], len = row_ptr[r + 1] - s;
  float acc = 0.f;
  for (int b = 0; b < len; b += 64) {
    int m  = min(64, len - b);
    int ev = (lane < m) ? csr_eid[s + b + lane] : 0;
    int j  = 0;
    for (; j + 4 <= m; j += 4) {
      int e0 = __shfl(ev, j),     e1 = __shfl(ev, j + 1);
      int e2 = __shfl(ev, j + 2), e3 = __shfl(ev, j + 3);
      float a0 = eattr[(size_t)e0 * 64 + lane];
      float a1 = eattr[(size_t)e1 * 64 + lane];
      float a2 = eattr[(size_t)e2 * 64 + lane];
      float a3 = eattr[(size_t)e3 * 64 + lane];
      acc += (a0 + a1) + (a2 + a3);
    }
    for (; j < m; ++j) {
      int e0 = __shfl(ev, j);
      acc += eattr[(size_t)e0 * 64 + lane];
    }
  }
  ST[(size_t)r * 192 + 128 + lane] = acc;
  if (lane == 0) deg[r] = fmaxf(1.0f, (float)len);
}

// ---------------------------------------------------------------------------
// S = segment_sum(h[col]) into ST[:,0:128]. One wave per row, float2 per lane.
// ---------------------------------------------------------------------------
__global__ __launch_bounds__(256) void scatter_S(
    const float* __restrict__ h, const int* __restrict__ row_ptr,
    const int* __restrict__ csr_col, float* __restrict__ ST, int N)
{
  int r = blockIdx.x * 4 + (threadIdx.x >> 6);
  if (r >= N) return;
  int lane = threadIdx.x & 63;
  int s = row_ptr[r], len = row_ptr[r + 1] - s;
  float2 acc = make_float2(0.f, 0.f);
  for (int b = 0; b < len; b += 64) {
    int m  = min(64, len - b);
    int cv = (lane < m) ? csr_col[s + b + lane] : 0;
    int j  = 0;
    for (; j + 4 <= m; j += 4) {
      int c0 = __shfl(cv, j),     c1 = __shfl(cv, j + 1);
      int c2 = __shfl(cv, j + 2), c3 = __shfl(cv, j + 3);
      float2 v0 = *reinterpret_cast<const float2*>(&h[(size_t)c0 * 128 + lane * 2]);
      float2 v1 = *reinterpret_cast<const float2*>(&h[(size_t)c1 * 128 + lane * 2]);
      float2 v2 = *reinterpret_cast<const float2*>(&h[(size_t)c2 * 128 + lane * 2]);
      float2 v3 = *reinterpret_cast<const float2*>(&h[(size_t)c3 * 128 + lane * 2]);
      acc.x += (v0.x + v1.x) + (v2.x + v3.x);
      acc.y += (v0.y + v1.y) + (v2.y + v3.y);
    }
    for (; j < m; ++j) {
      int c0 = __shfl(cv, j);
      float2 v0 = *reinterpret_cast<const float2*>(&h[(size_t)c0 * 128 + lane * 2]);
      acc.x += v0.x; acc.y += v0.y;
    }
  }
  *reinterpret_cast<float2*>(&ST[(size_t)r * 192 + lane * 2]) = acc;
}

// ---------------------------------------------------------------------------
// Per-graph mean pool + hidden relu + output head. One block (128 thr) per graph.
// ---------------------------------------------------------------------------
__global__ __launch_bounds__(128) void pool_head(
    const float* __restrict__ h, const int* __restrict__ batch,
    const float* __restrict__ Wh, const float* __restrict__ bh,
    const float* __restrict__ Wout, const float* __restrict__ bout,
    float* __restrict__ out, int N)
{
  const int g = blockIdx.x;
  const int t = threadIdx.x;
  // lower_bound(g) and lower_bound(g+1) over sorted batch
  int lo = 0, hi = N;
  while (lo < hi) { int mid = (lo + hi) >> 1; if (batch[mid] < g) lo = mid + 1; else hi = mid; }
  int start = lo;
  hi = N;
  while (lo < hi) { int mid = (lo + hi) >> 1; if (batch[mid] < g + 1) lo = mid + 1; else hi = mid; }
  int end = lo;

  float sum = 0.f;
  for (int i = start; i < end; i++) sum += h[(size_t)i * 128 + t];
  float inv = 1.f / fmaxf(1.f, (float)(end - start));

  __shared__ float gl[128];
  gl[t] = sum * inv;
  __syncthreads();

  float acc = bh[t];
  for (int k = 0; k < 128; k++) acc += gl[k] * Wh[k * 128 + t];
  acc = fmaxf(acc, 0.f);

  __shared__ float p[128];
  p[t] = acc * Wout[t];
  __syncthreads();
  if (t < 64) {
    float v = p[t] + p[t + 64];
    #pragma unroll
    for (int o = 32; o > 0; o >>= 1) v += __shfl_down(v, o);
    if (t == 0) out[g] = v + bout[0];
  }
}

// ---------------------------------------------------------------------------
extern "C" void kernel_launch(void* const* d_in, const int* in_sizes, int n_in,
                              void* d_out, int out_size, void* d_ws, size_t ws_size,
                              hipStream_t stream)
{
  const float* x      = (const float*)d_in[0];
  const int*   eidx   = (const int*)d_in[1];
  const float* eattr  = (const float*)d_in[2];
  const int*   batch  = (const int*)d_in[3];
  const float* W_emb  = (const float*)d_in[4];
  const float* b_emb  = (const float*)d_in[5];
  const float* Wc     = (const float*)d_in[6];
  const float* bc     = (const float*)d_in[7];
  const float* gamma  = (const float*)d_in[8];
  const float* beta   = (const float*)d_in[9];
  const float* Wh     = (const float*)d_in[10];
  const float* bh     = (const float*)d_in[11];
  const float* Wout   = (const float*)d_in[12];
  const float* bout   = (const float*)d_in[13];
  float* out = (float*)d_out;

  const int N  = in_sizes[3];
  const int E  = in_sizes[1] / 2;
  const int Fn = in_sizes[0] / N;      // 92
  const int H  = in_sizes[5];          // 128
  const int L  = in_sizes[7] / H;      // 3
  const int Kc = H + in_sizes[2] / E;  // 192

  const int* rows = eidx;
  const int* cols = eidx + E;

  char* ws = (char*)d_ws;
  size_t off = 0;
  auto alloc = [&](size_t bytes) { void* p = ws + off; off += (bytes + 255) / 256 * 256; return p; };
  float* h        = (float*)alloc((size_t)N * 128 * 4);
  float* ST       = (float*)alloc((size_t)N * 192 * 4);
  float* deg      = (float*)alloc((size_t)N * 4);
  int*   row_ptr  = (int*)alloc((size_t)(N + 1) * 4);
  int*   cnt      = (int*)alloc((size_t)N * 4 * 2);   // hist cnt + fill cnt, contiguous
  int*   fill_cnt = cnt + N;
  int*   csr_col  = (int*)alloc((size_t)E * 4);
  int*   csr_eid  = (int*)alloc((size_t)E * 4);
  (void)ws_size; (void)n_in;

  hipMemsetAsync(cnt, 0, (size_t)N * 8, stream);

  // h = relu(x @ W_emb + b_emb)
  gemm128<0><<<dim3((N + 63) / 64), 256, 0, stream>>>(
      x, Fn, Fn, N, W_emb, b_emb, nullptr, nullptr, nullptr, nullptr, h);

  // CSR
  hist_kernel<<<dim3((E + 255) / 256), 256, 0, stream>>>(rows, cnt, E);
  scan_kernel<<<dim3(1), 1024, 0, stream>>>(cnt, row_ptr, N);
  fill_kernel<<<dim3((E + 255) / 256), 256, 0, stream>>>(rows, cols, row_ptr, fill_cnt,
                                                         csr_col, csr_eid, E);
  // T (layer-invariant) + deg
  build_T_deg<<<dim3((N + 3) / 4), 256, 0, stream>>>(eattr, row_ptr, csr_eid, ST, deg, N);

  // conv layers
  for (int l = 0; l < L; l++) {
    scatter_S<<<dim3((N + 3) / 4), 256, 0, stream>>>(h, row_ptr, csr_col, ST, N);
    gemm128<1><<<dim3((N + 63) / 64), 256, 0, stream>>>(
        ST, Kc, Kc, N, Wc + (size_t)l * Kc * H, nullptr, deg,
        bc + (size_t)l * H, gamma + (size_t)l * H, beta + (size_t)l * H, h);
  }

  // pool + head
  pool_head<<<dim3(out_size), 128, 0, stream>>>(h, batch, Wh, bh, Wout, bout, out, N);
}

// Round 2
// 530.893 us; speedup vs baseline: 1.1655x; 1.1655x over previous
//
#include <hip/hip_runtime.h>
#include <hip/hip_bf16.h>
#include <cstdint>
#include <cstddef>

#define BN_EPS 1e-3f

typedef __attribute__((ext_vector_type(8))) short bf16x8;
typedef __attribute__((ext_vector_type(4))) float f32x4;

// ---------------------------------------------------------------------------
// fp32 GEMM for embedding: out-tile 64x128, A [N x K], B [K x 128].
// h = relu(A@B + bias)
// ---------------------------------------------------------------------------
__global__ __launch_bounds__(256) void gemm_emb(
    const float* __restrict__ A, int lda, int K, int N,
    const float* __restrict__ B,
    const float* __restrict__ bias,
    float* __restrict__ h)
{
  __shared__ float As[64][33];
  __shared__ float Bs[32][128];
  const int tid = threadIdx.x;
  const int tx = tid & 31;
  const int ty = tid >> 5;
  const int m0 = blockIdx.x * 64;

  float acc[8][4];
  #pragma unroll
  for (int r = 0; r < 8; r++)
    #pragma unroll
    for (int q = 0; q < 4; q++) acc[r][q] = 0.f;

  for (int k0 = 0; k0 < K; k0 += 32) {
    #pragma unroll
    for (int i = 0; i < 2; i++) {
      int f  = tid + i * 256;
      int r  = f >> 3;
      int kq = (f & 7) * 4;
      float4 v = make_float4(0.f, 0.f, 0.f, 0.f);
      int gr = m0 + r;
      if (gr < N) {
        if (k0 + kq + 4 <= K) {
          v = *reinterpret_cast<const float4*>(&A[(size_t)gr * lda + k0 + kq]);
        } else {
          float t0 = (k0 + kq + 0 < K) ? A[(size_t)gr * lda + k0 + kq + 0] : 0.f;
          float t1 = (k0 + kq + 1 < K) ? A[(size_t)gr * lda + k0 + kq + 1] : 0.f;
          float t2 = (k0 + kq + 2 < K) ? A[(size_t)gr * lda + k0 + kq + 2] : 0.f;
          float t3 = (k0 + kq + 3 < K) ? A[(size_t)gr * lda + k0 + kq + 3] : 0.f;
          v = make_float4(t0, t1, t2, t3);
        }
      }
      As[r][kq + 0] = v.x; As[r][kq + 1] = v.y;
      As[r][kq + 2] = v.z; As[r][kq + 3] = v.w;
    }
    #pragma unroll
    for (int i = 0; i < 4; i++) {
      int f4   = tid + i * 256;
      int flat = f4 * 4;
      int k = flat >> 7;
      int j = flat & 127;
      float4 v = make_float4(0.f, 0.f, 0.f, 0.f);
      if (k0 + k < K)
        v = *reinterpret_cast<const float4*>(&B[(size_t)(k0 + k) * 128 + j]);
      *reinterpret_cast<float4*>(&Bs[k][j]) = v;
    }
    __syncthreads();
    #pragma unroll
    for (int k = 0; k < 32; k++) {
      float4 b = *reinterpret_cast<const float4*>(&Bs[k][tx * 4]);
      #pragma unroll
      for (int r = 0; r < 8; r++) {
        float a = As[ty * 8 + r][k];
        acc[r][0] += a * b.x; acc[r][1] += a * b.y;
        acc[r][2] += a * b.z; acc[r][3] += a * b.w;
      }
    }
    __syncthreads();
  }

  const int c = tx * 4;
  float4 bb = *reinterpret_cast<const float4*>(&bias[c]);
  #pragma unroll
  for (int r = 0; r < 8; r++) {
    int gr = m0 + ty * 8 + r;
    if (gr < N) {
      float4 o;
      o.x = fmaxf(acc[r][0] + bb.x, 0.f);
      o.y = fmaxf(acc[r][1] + bb.y, 0.f);
      o.z = fmaxf(acc[r][2] + bb.z, 0.f);
      o.w = fmaxf(acc[r][3] + bb.w, 0.f);
      *reinterpret_cast<float4*>(&h[(size_t)gr * 128 + c]) = o;
    }
  }
}

// ---------------------------------------------------------------------------
// bf16 MFMA GEMM for conv layers. A = STb [N x 192] bf16, B = Wct [128 x 192]
// bf16 (pre-transposed: row = out col, contiguous k). 64 rows x 128 cols per
// block, 4 waves in 2x2, each wave 32x64 via 2x4 16x16x32 fragments.
// Epilogue: h += relu(acc/deg * bn_scale + (bc*bn_scale + beta))  [fp32]
// ---------------------------------------------------------------------------
__global__ __launch_bounds__(256) void gemm_conv(
    const __hip_bfloat16* __restrict__ STb,
    const __hip_bfloat16* __restrict__ Wct,
    const float* __restrict__ deg,
    const float* __restrict__ bc,
    const float* __restrict__ gamma,
    const float* __restrict__ beta,
    float* __restrict__ h, int N, int K)
{
  const int tid  = threadIdx.x;
  const int w    = tid >> 6, lane = tid & 63;
  const int wr   = w >> 1,   wc   = w & 1;
  const int m0   = blockIdx.x * 64;
  const int lr   = lane & 15;   // row (A) / col (B) within fragment
  const int kg   = lane >> 4;   // k-group: 8 contiguous k each

  f32x4 acc[2][4] = {};
  const int rowA0 = m0 + wr * 32 + lr;

  #pragma unroll 6
  for (int ks = 0; ks < K / 32; ks++) {
    const int k0 = ks * 32 + kg * 8;
    bf16x8 a[2], b[4];
    #pragma unroll
    for (int m = 0; m < 2; m++) {
      int r = rowA0 + m * 16;
      r = (r < N) ? r : 0;          // clamp; result discarded in epilogue
      a[m] = *reinterpret_cast<const bf16x8*>(&STb[(size_t)r * K + k0]);
    }
    #pragma unroll
    for (int n = 0; n < 4; n++) {
      int c = wc * 64 + n * 16 + lr;
      b[n] = *reinterpret_cast<const bf16x8*>(&Wct[(size_t)c * K + k0]);
    }
    #pragma unroll
    for (int m = 0; m < 2; m++)
      #pragma unroll
      for (int n = 0; n < 4; n++)
        acc[m][n] = __builtin_amdgcn_mfma_f32_16x16x32_bf16(a[m], b[n], acc[m][n], 0, 0, 0);
  }

  const float rs = rsqrtf(1.f + BN_EPS);
  #pragma unroll
  for (int n = 0; n < 4; n++) {
    const int c   = wc * 64 + n * 16 + lr;
    const float sc  = gamma[c] * rs;
    const float ofs = bc[c] * sc + beta[c];
    #pragma unroll
    for (int m = 0; m < 2; m++) {
      #pragma unroll
      for (int j = 0; j < 4; j++) {
        int grow = m0 + wr * 32 + m * 16 + kg * 4 + j;
        if (grow < N) {
          float id = 1.f / deg[grow];
          float v  = acc[m][n][j] * sc * id + ofs;
          h[(size_t)grow * 128 + c] += fmaxf(v, 0.f);
        }
      }
    }
  }
}

// ---------------------------------------------------------------------------
// Wc [L][K][H] fp32  ->  Wct [L][H][K] bf16 (transposed per layer)
// ---------------------------------------------------------------------------
__global__ void prep_wct(const float* __restrict__ Wc, __hip_bfloat16* __restrict__ Wct,
                         int total, int K, int H)
{
  int i = blockIdx.x * 256 + threadIdx.x;
  if (i >= total) return;
  int l   = i / (K * H);
  int rem = i - l * (K * H);
  int k   = rem / H;
  int c   = rem - k * H;
  Wct[(size_t)l * H * K + (size_t)c * K + k] = __float2bfloat16(Wc[i]);
}

// ---------------------------------------------------------------------------
// CSR build
// ---------------------------------------------------------------------------
__global__ void hist_kernel(const int* __restrict__ rows, int* __restrict__ cnt, int E) {
  int e = blockIdx.x * 256 + threadIdx.x;
  if (e < E) atomicAdd(&cnt[rows[e]], 1);
}

__global__ __launch_bounds__(1024) void scan_kernel(const int* __restrict__ cnt,
                                                    int* __restrict__ row_ptr, int N) {
  __shared__ int wsum[16];
  __shared__ int woff[16];
  __shared__ int carry;
  const int tid  = threadIdx.x;
  const int lane = tid & 63, wid = tid >> 6;
  if (tid == 0) { carry = 0; row_ptr[0] = 0; }
  __syncthreads();
  for (int base = 0; base < N; base += 8192) {
    int c = carry;
    int v[8]; int s = 0;
    #pragma unroll
    for (int i = 0; i < 8; i++) {
      int idx = base + tid * 8 + i;
      v[i] = (idx < N) ? cnt[idx] : 0;
      s += v[i];
    }
    int sc = s;
    #pragma unroll
    for (int o = 1; o < 64; o <<= 1) {
      int u = __shfl_up(sc, o);
      if (lane >= o) sc += u;
    }
    if (lane == 63) wsum[wid] = sc;
    __syncthreads();
    if (tid == 0) {
      int run = 0;
      for (int i = 0; i < 16; i++) { int t = wsum[i]; woff[i] = run; run += t; }
      carry = c + run;
    }
    __syncthreads();
    int run = c + woff[wid] + (sc - s);
    #pragma unroll
    for (int i = 0; i < 8; i++) {
      int idx = base + tid * 8 + i;
      run += v[i];
      if (idx < N) row_ptr[idx + 1] = run;
    }
  }
}

__global__ void fill_kernel(const int* __restrict__ rows, const int* __restrict__ cols,
                            const int* __restrict__ row_ptr, int* __restrict__ fill_cnt,
                            int* __restrict__ csr_col, int* __restrict__ csr_eid, int E) {
  int e = blockIdx.x * 256 + threadIdx.x;
  if (e < E) {
    int r   = rows[e];
    int pos = atomicAdd(&fill_cnt[r], 1);
    int at  = row_ptr[r] + pos;
    csr_col[at] = cols[e];
    csr_eid[at] = e;
  }
}

// ---------------------------------------------------------------------------
// T = segment_sum(edge_attr) into STb[:,128:192] (bf16); deg from CSR.
// ---------------------------------------------------------------------------
__global__ __launch_bounds__(256) void build_T_deg(
    const float* __restrict__ eattr, const int* __restrict__ row_ptr,
    const int* __restrict__ csr_eid, __hip_bfloat16* __restrict__ STb,
    float* __restrict__ deg, int N)
{
  int r = blockIdx.x * 4 + (threadIdx.x >> 6);
  if (r >= N) return;
  int lane = threadIdx.x & 63;
  int s = row_ptr[r], len = row_ptr[r + 1] - s;
  float acc = 0.f;
  for (int b = 0; b < len; b += 64) {
    int m  = min(64, len - b);
    int ev = (lane < m) ? csr_eid[s + b + lane] : 0;
    int j  = 0;
    for (; j + 4 <= m; j += 4) {
      int e0 = __shfl(ev, j),     e1 = __shfl(ev, j + 1);
      int e2 = __shfl(ev, j + 2), e3 = __shfl(ev, j + 3);
      float a0 = eattr[(size_t)e0 * 64 + lane];
      float a1 = eattr[(size_t)e1 * 64 + lane];
      float a2 = eattr[(size_t)e2 * 64 + lane];
      float a3 = eattr[(size_t)e3 * 64 + lane];
      acc += (a0 + a1) + (a2 + a3);
    }
    for (; j < m; ++j) {
      int e0 = __shfl(ev, j);
      acc += eattr[(size_t)e0 * 64 + lane];
    }
  }
  STb[(size_t)r * 192 + 128 + lane] = __float2bfloat16(acc);
  if (lane == 0) deg[r] = fmaxf(1.0f, (float)len);
}

// ---------------------------------------------------------------------------
// S = segment_sum(h[col]) into STb[:,0:128] (bf16). One wave per row.
// ---------------------------------------------------------------------------
__global__ __launch_bounds__(256) void scatter_S(
    const float* __restrict__ h, const int* __restrict__ row_ptr,
    const int* __restrict__ csr_col, __hip_bfloat16* __restrict__ STb, int N)
{
  int r = blockIdx.x * 4 + (threadIdx.x >> 6);
  if (r >= N) return;
  int lane = threadIdx.x & 63;
  int s = row_ptr[r], len = row_ptr[r + 1] - s;
  float2 acc = make_float2(0.f, 0.f);
  for (int b = 0; b < len; b += 64) {
    int m  = min(64, len - b);
    int cv = (lane < m) ? csr_col[s + b + lane] : 0;
    int j  = 0;
    for (; j + 4 <= m; j += 4) {
      int c0 = __shfl(cv, j),     c1 = __shfl(cv, j + 1);
      int c2 = __shfl(cv, j + 2), c3 = __shfl(cv, j + 3);
      float2 v0 = *reinterpret_cast<const float2*>(&h[(size_t)c0 * 128 + lane * 2]);
      float2 v1 = *reinterpret_cast<const float2*>(&h[(size_t)c1 * 128 + lane * 2]);
      float2 v2 = *reinterpret_cast<const float2*>(&h[(size_t)c2 * 128 + lane * 2]);
      float2 v3 = *reinterpret_cast<const float2*>(&h[(size_t)c3 * 128 + lane * 2]);
      acc.x += (v0.x + v1.x) + (v2.x + v3.x);
      acc.y += (v0.y + v1.y) + (v2.y + v3.y);
    }
    for (; j < m; ++j) {
      int c0 = __shfl(cv, j);
      float2 v0 = *reinterpret_cast<const float2*>(&h[(size_t)c0 * 128 + lane * 2]);
      acc.x += v0.x; acc.y += v0.y;
    }
  }
  __hip_bfloat162 o = __float22bfloat162_rn(acc);
  *reinterpret_cast<__hip_bfloat162*>(&STb[(size_t)r * 192 + lane * 2]) = o;
}

// ---------------------------------------------------------------------------
// Per-graph mean pool + hidden relu + output head. One block per graph.
// ---------------------------------------------------------------------------
__global__ __launch_bounds__(128) void pool_head(
    const float* __restrict__ h, const int* __restrict__ batch,
    const float* __restrict__ Wh, const float* __restrict__ bh,
    const float* __restrict__ Wout, const float* __restrict__ bout,
    float* __restrict__ out, int N)
{
  const int g = blockIdx.x;
  const int t = threadIdx.x;
  int lo = 0, hi = N;
  while (lo < hi) { int mid = (lo + hi) >> 1; if (batch[mid] < g) lo = mid + 1; else hi = mid; }
  int start = lo;
  hi = N;
  while (lo < hi) { int mid = (lo + hi) >> 1; if (batch[mid] < g + 1) lo = mid + 1; else hi = mid; }
  int end = lo;

  float sum = 0.f;
  for (int i = start; i < end; i++) sum += h[(size_t)i * 128 + t];
  float inv = 1.f / fmaxf(1.f, (float)(end - start));

  __shared__ float gl[128];
  gl[t] = sum * inv;
  __syncthreads();

  float acc = bh[t];
  for (int k = 0; k < 128; k++) acc += gl[k] * Wh[k * 128 + t];
  acc = fmaxf(acc, 0.f);

  __shared__ float p[128];
  p[t] = acc * Wout[t];
  __syncthreads();
  if (t < 64) {
    float v = p[t] + p[t + 64];
    #pragma unroll
    for (int o = 32; o > 0; o >>= 1) v += __shfl_down(v, o);
    if (t == 0) out[g] = v + bout[0];
  }
}

// ---------------------------------------------------------------------------
extern "C" void kernel_launch(void* const* d_in, const int* in_sizes, int n_in,
                              void* d_out, int out_size, void* d_ws, size_t ws_size,
                              hipStream_t stream)
{
  const float* x      = (const float*)d_in[0];
  const int*   eidx   = (const int*)d_in[1];
  const float* eattr  = (const float*)d_in[2];
  const int*   batch  = (const int*)d_in[3];
  const float* W_emb  = (const float*)d_in[4];
  const float* b_emb  = (const float*)d_in[5];
  const float* Wc     = (const float*)d_in[6];
  const float* bc     = (const float*)d_in[7];
  const float* gamma  = (const float*)d_in[8];
  const float* beta   = (const float*)d_in[9];
  const float* Wh     = (const float*)d_in[10];
  const float* bh     = (const float*)d_in[11];
  const float* Wout   = (const float*)d_in[12];
  const float* bout   = (const float*)d_in[13];
  float* out = (float*)d_out;

  const int N  = in_sizes[3];
  const int E  = in_sizes[1] / 2;
  const int Fn = in_sizes[0] / N;      // 92
  const int H  = in_sizes[5];          // 128
  const int L  = in_sizes[7] / H;      // 3
  const int Kc = H + in_sizes[2] / E;  // 192

  const int* rows = eidx;
  const int* cols = eidx + E;

  char* ws = (char*)d_ws;
  size_t off = 0;
  auto alloc = [&](size_t bytes) { void* p = ws + off; off += (bytes + 255) / 256 * 256; return p; };
  float*           h        = (float*)alloc((size_t)N * 128 * 4);
  __hip_bfloat16*  STb      = (__hip_bfloat16*)alloc((size_t)N * Kc * 2);
  __hip_bfloat16*  Wct      = (__hip_bfloat16*)alloc((size_t)L * H * Kc * 2);
  float*           deg      = (float*)alloc((size_t)N * 4);
  int*             row_ptr  = (int*)alloc((size_t)(N + 1) * 4);
  int*             cnt      = (int*)alloc((size_t)N * 4 * 2);
  int*             fill_cnt = cnt + N;
  int*             csr_col  = (int*)alloc((size_t)E * 4);
  int*             csr_eid  = (int*)alloc((size_t)E * 4);
  (void)ws_size; (void)n_in;

  hipMemsetAsync(cnt, 0, (size_t)N * 8, stream);

  // h = relu(x @ W_emb + b_emb)   [fp32]
  gemm_emb<<<dim3((N + 63) / 64), 256, 0, stream>>>(x, Fn, Fn, N, W_emb, b_emb, h);

  // Wc -> bf16 transposed [L][H][Kc]
  prep_wct<<<dim3((L * Kc * H + 255) / 256), 256, 0, stream>>>(Wc, Wct, L * Kc * H, Kc, H);

  // CSR
  hist_kernel<<<dim3((E + 255) / 256), 256, 0, stream>>>(rows, cnt, E);
  scan_kernel<<<dim3(1), 1024, 0, stream>>>(cnt, row_ptr, N);
  fill_kernel<<<dim3((E + 255) / 256), 256, 0, stream>>>(rows, cols, row_ptr, fill_cnt,
                                                         csr_col, csr_eid, E);
  // T (layer-invariant, bf16) + deg
  build_T_deg<<<dim3((N + 3) / 4), 256, 0, stream>>>(eattr, row_ptr, csr_eid, STb, deg, N);

  // conv layers: S gather (bf16) + MFMA GEMM with fused epilogue
  for (int l = 0; l < L; l++) {
    scatter_S<<<dim3((N + 3) / 4), 256, 0, stream>>>(h, row_ptr, csr_col, STb, N);
    gemm_conv<<<dim3((N + 63) / 64), 256, 0, stream>>>(
        STb, Wct + (size_t)l * H * Kc, deg,
        bc + (size_t)l * H, gamma + (size_t)l * H, beta + (size_t)l * H, h, N, Kc);
  }

  // pool + head
  pool_head<<<dim3(out_size), 128, 0, stream>>>(h, batch, Wh, bh, Wout, bout, out, N);
}

// Round 3
// 464.462 us; speedup vs baseline: 1.3322x; 1.1430x over previous
//
#include <hip/hip_runtime.h>
#include <hip/hip_bf16.h>
#include <cstdint>
#include <cstddef>

#define BN_EPS 1e-3f

typedef __attribute__((ext_vector_type(8))) short bf16x8;
typedef __attribute__((ext_vector_type(4))) float f32x4;

__device__ __forceinline__ float blo(unsigned u) {
  union { unsigned i; float f; } v; v.i = u << 16; return v.f;
}
__device__ __forceinline__ float bhi(unsigned u) {
  union { unsigned i; float f; } v; v.i = u & 0xffff0000u; return v.f;
}

// ---------------------------------------------------------------------------
// bf16 MFMA GEMM, 64 rows x 128 cols per block, 4 waves 2x2, wave = 32x64 via
// 2x4 16x16x32 fragments. A [N][K] bf16, Bt [128][K] bf16 (row = out col).
// MODE 0 (embedding): h = relu(acc + bias);      hb = bf16(h)
// MODE 1 (conv):      h += relu(acc/deg * bn_scale + (bc*bn_scale + beta)); hb = bf16(h)
// ---------------------------------------------------------------------------
template<int MODE, int K>
__global__ __launch_bounds__(256) void gemm_mfma(
    const __hip_bfloat16* __restrict__ A,
    const __hip_bfloat16* __restrict__ Bt,
    const float* __restrict__ bias,
    const float* __restrict__ deg,
    const float* __restrict__ bc,
    const float* __restrict__ gamma,
    const float* __restrict__ beta,
    float* __restrict__ h,
    __hip_bfloat16* __restrict__ hb, int N)
{
  const int tid  = threadIdx.x;
  const int w    = tid >> 6, lane = tid & 63;
  const int wr   = w >> 1,   wc   = w & 1;
  const int m0   = blockIdx.x * 64;
  const int lr   = lane & 15;
  const int kg   = lane >> 4;

  f32x4 acc[2][4] = {};
  const int rowA0 = m0 + wr * 32 + lr;

  #pragma unroll
  for (int ks = 0; ks < K / 32; ks++) {
    const int k0 = ks * 32 + kg * 8;
    bf16x8 a[2], b[4];
    #pragma unroll
    for (int m = 0; m < 2; m++) {
      int r = rowA0 + m * 16;
      r = (r < N) ? r : 0;
      a[m] = *reinterpret_cast<const bf16x8*>(&A[(size_t)r * K + k0]);
    }
    #pragma unroll
    for (int n = 0; n < 4; n++) {
      int c = wc * 64 + n * 16 + lr;
      b[n] = *reinterpret_cast<const bf16x8*>(&Bt[(size_t)c * K + k0]);
    }
    #pragma unroll
    for (int m = 0; m < 2; m++)
      #pragma unroll
      for (int n = 0; n < 4; n++)
        acc[m][n] = __builtin_amdgcn_mfma_f32_16x16x32_bf16(a[m], b[n], acc[m][n], 0, 0, 0);
  }

  if (MODE == 0) {
    #pragma unroll
    for (int n = 0; n < 4; n++) {
      const int c = wc * 64 + n * 16 + lr;
      const float bb = bias[c];
      #pragma unroll
      for (int m = 0; m < 2; m++) {
        #pragma unroll
        for (int j = 0; j < 4; j++) {
          int grow = m0 + wr * 32 + m * 16 + kg * 4 + j;
          if (grow < N) {
            float v = fmaxf(acc[m][n][j] + bb, 0.f);
            h[(size_t)grow * 128 + c]  = v;
            hb[(size_t)grow * 128 + c] = __float2bfloat16(v);
          }
        }
      }
    }
  } else {
    const float rs = rsqrtf(1.f + BN_EPS);
    #pragma unroll
    for (int n = 0; n < 4; n++) {
      const int c   = wc * 64 + n * 16 + lr;
      const float sc  = gamma[c] * rs;
      const float ofs = bc[c] * sc + beta[c];
      #pragma unroll
      for (int m = 0; m < 2; m++) {
        #pragma unroll
        for (int j = 0; j < 4; j++) {
          int grow = m0 + wr * 32 + m * 16 + kg * 4 + j;
          if (grow < N) {
            float id = 1.f / deg[grow];
            float v  = acc[m][n][j] * sc * id + ofs;
            float hn = h[(size_t)grow * 128 + c] + fmaxf(v, 0.f);
            h[(size_t)grow * 128 + c]  = hn;
            hb[(size_t)grow * 128 + c] = __float2bfloat16(hn);
          }
        }
      }
    }
  }
}

// ---------------------------------------------------------------------------
// One-shot prep: xb [N][96] bf16 (pad 92->96), Wet [128][96] bf16 (transposed,
// padded), Wct [L][128][192] bf16 (transposed), zero cnt/fill_cnt.
// ---------------------------------------------------------------------------
__global__ void prep_all(const float* __restrict__ x, __hip_bfloat16* __restrict__ xb,
                         const float* __restrict__ W_emb, __hip_bfloat16* __restrict__ Wet,
                         const float* __restrict__ Wc, __hip_bfloat16* __restrict__ Wct,
                         int* __restrict__ cnt,
                         int N, int Fn, int Kp, int H, int L, int Kc, int total)
{
  int i = blockIdx.x * 256 + threadIdx.x;
  if (i < N * Kp) {
    int r = i / Kp, k = i - r * Kp;
    xb[i] = __float2bfloat16(k < Fn ? x[(size_t)r * Fn + k] : 0.f);
  } else if (i < N * Kp + H * Kp) {
    int j = i - N * Kp;
    int c = j / Kp, k = j - c * Kp;
    Wet[j] = __float2bfloat16(k < Fn ? W_emb[(size_t)k * H + c] : 0.f);
  } else if (i < total) {
    int j = i - N * Kp - H * Kp;          // over L*H*Kc, layout [l][c][k]
    int l   = j / (H * Kc);
    int rem = j - l * (H * Kc);
    int c   = rem / Kc;
    int k   = rem - c * Kc;
    Wct[j] = __float2bfloat16(Wc[(size_t)l * Kc * H + (size_t)k * H + c]);
  }
  if (i < 2 * N) cnt[i] = 0;
}

// ---------------------------------------------------------------------------
// CSR build
// ---------------------------------------------------------------------------
__global__ void hist_kernel(const int* __restrict__ rows, int* __restrict__ cnt, int E) {
  int e = blockIdx.x * 256 + threadIdx.x;
  if (e < E) atomicAdd(&cnt[rows[e]], 1);
}

__global__ __launch_bounds__(1024) void scan_kernel(const int* __restrict__ cnt,
                                                    int* __restrict__ row_ptr, int N) {
  __shared__ int wsum[16];
  __shared__ int woff[16];
  __shared__ int carry;
  const int tid  = threadIdx.x;
  const int lane = tid & 63, wid = tid >> 6;
  if (tid == 0) { carry = 0; row_ptr[0] = 0; }
  __syncthreads();
  for (int base = 0; base < N; base += 8192) {
    int c = carry;
    int v[8]; int s = 0;
    #pragma unroll
    for (int i = 0; i < 8; i++) {
      int idx = base + tid * 8 + i;
      v[i] = (idx < N) ? cnt[idx] : 0;
      s += v[i];
    }
    int sc = s;
    #pragma unroll
    for (int o = 1; o < 64; o <<= 1) {
      int u = __shfl_up(sc, o);
      if (lane >= o) sc += u;
    }
    if (lane == 63) wsum[wid] = sc;
    __syncthreads();
    if (tid == 0) {
      int run = 0;
      for (int i = 0; i < 16; i++) { int t = wsum[i]; woff[i] = run; run += t; }
      carry = c + run;
    }
    __syncthreads();
    int run = c + woff[wid] + (sc - s);
    #pragma unroll
    for (int i = 0; i < 8; i++) {
      int idx = base + tid * 8 + i;
      run += v[i];
      if (idx < N) row_ptr[idx + 1] = run;
    }
  }
}

__global__ void fill_kernel(const int* __restrict__ rows, const int* __restrict__ cols,
                            const int* __restrict__ row_ptr, int* __restrict__ fill_cnt,
                            int* __restrict__ csr_col, int* __restrict__ csr_eid, int E) {
  int e = blockIdx.x * 256 + threadIdx.x;
  if (e < E) {
    int r   = rows[e];
    int pos = atomicAdd(&fill_cnt[r], 1);
    int at  = row_ptr[r] + pos;
    csr_col[at] = cols[e];
    csr_eid[at] = e;
  }
}

// ---------------------------------------------------------------------------
// T = segment_sum(edge_attr) into STb[:,128:192] (bf16); deg from CSR.
// ---------------------------------------------------------------------------
__global__ __launch_bounds__(256) void build_T_deg(
    const float* __restrict__ eattr, const int* __restrict__ row_ptr,
    const int* __restrict__ csr_eid, __hip_bfloat16* __restrict__ STb,
    float* __restrict__ deg, int N)
{
  int r = blockIdx.x * 4 + (threadIdx.x >> 6);
  if (r >= N) return;
  int lane = threadIdx.x & 63;
  int s = row_ptr[r], len = row_ptr[r + 1] - s;
  float acc = 0.f;
  for (int b = 0; b < len; b += 64) {
    int m  = min(64, len - b);
    int ev = (lane < m) ? csr_eid[s + b + lane] : 0;
    int j  = 0;
    for (; j + 4 <= m; j += 4) {
      int e0 = __shfl(ev, j),     e1 = __shfl(ev, j + 1);
      int e2 = __shfl(ev, j + 2), e3 = __shfl(ev, j + 3);
      float a0 = eattr[(size_t)e0 * 64 + lane];
      float a1 = eattr[(size_t)e1 * 64 + lane];
      float a2 = eattr[(size_t)e2 * 64 + lane];
      float a3 = eattr[(size_t)e3 * 64 + lane];
      acc += (a0 + a1) + (a2 + a3);
    }
    for (; j < m; ++j) {
      int e0 = __shfl(ev, j);
      acc += eattr[(size_t)e0 * 64 + lane];
    }
  }
  STb[(size_t)r * 192 + 128 + lane] = __float2bfloat16(acc);
  if (lane == 0) deg[r] = fmaxf(1.0f, (float)len);
}

// ---------------------------------------------------------------------------
// S = segment_sum(hb[col]) into STb[:,0:128]. bf16 gather (4B/lane), fp32 acc.
// ---------------------------------------------------------------------------
__global__ __launch_bounds__(256) void scatter_S(
    const __hip_bfloat16* __restrict__ hb, const int* __restrict__ row_ptr,
    const int* __restrict__ csr_col, __hip_bfloat16* __restrict__ STb, int N)
{
  int r = blockIdx.x * 4 + (threadIdx.x >> 6);
  if (r >= N) return;
  int lane = threadIdx.x & 63;
  int s = row_ptr[r], len = row_ptr[r + 1] - s;
  float2 acc = make_float2(0.f, 0.f);
  for (int b = 0; b < len; b += 64) {
    int m  = min(64, len - b);
    int cv = (lane < m) ? csr_col[s + b + lane] : 0;
    int j  = 0;
    for (; j + 8 <= m; j += 8) {
      unsigned u[8];
      #pragma unroll
      for (int t = 0; t < 8; t++) {
        int c = __shfl(cv, j + t);
        u[t] = *reinterpret_cast<const unsigned*>(&hb[(size_t)c * 128 + lane * 2]);
      }
      #pragma unroll
      for (int t = 0; t < 8; t++) { acc.x += blo(u[t]); acc.y += bhi(u[t]); }
    }
    for (; j < m; ++j) {
      int c = __shfl(cv, j);
      unsigned u = *reinterpret_cast<const unsigned*>(&hb[(size_t)c * 128 + lane * 2]);
      acc.x += blo(u); acc.y += bhi(u);
    }
  }
  __hip_bfloat162 o = __float22bfloat162_rn(acc);
  *reinterpret_cast<__hip_bfloat162*>(&STb[(size_t)r * 192 + lane * 2]) = o;
}

// ---------------------------------------------------------------------------
// Per-graph mean pool + hidden relu + output head. One block per graph.
// ---------------------------------------------------------------------------
__global__ __launch_bounds__(128) void pool_head(
    const float* __restrict__ h, const int* __restrict__ batch,
    const float* __restrict__ Wh, const float* __restrict__ bh,
    const float* __restrict__ Wout, const float* __restrict__ bout,
    float* __restrict__ out, int N)
{
  const int g = blockIdx.x;
  const int t = threadIdx.x;
  int lo = 0, hi = N;
  while (lo < hi) { int mid = (lo + hi) >> 1; if (batch[mid] < g) lo = mid + 1; else hi = mid; }
  int start = lo;
  hi = N;
  while (lo < hi) { int mid = (lo + hi) >> 1; if (batch[mid] < g + 1) lo = mid + 1; else hi = mid; }
  int end = lo;

  float sum = 0.f;
  for (int i = start; i < end; i++) sum += h[(size_t)i * 128 + t];
  float inv = 1.f / fmaxf(1.f, (float)(end - start));

  __shared__ float gl[128];
  gl[t] = sum * inv;
  __syncthreads();

  float acc = bh[t];
  for (int k = 0; k < 128; k++) acc += gl[k] * Wh[k * 128 + t];
  acc = fmaxf(acc, 0.f);

  __shared__ float p[128];
  p[t] = acc * Wout[t];
  __syncthreads();
  if (t < 64) {
    float v = p[t] + p[t + 64];
    #pragma unroll
    for (int o = 32; o > 0; o >>= 1) v += __shfl_down(v, o);
    if (t == 0) out[g] = v + bout[0];
  }
}

// ---------------------------------------------------------------------------
extern "C" void kernel_launch(void* const* d_in, const int* in_sizes, int n_in,
                              void* d_out, int out_size, void* d_ws, size_t ws_size,
                              hipStream_t stream)
{
  const float* x      = (const float*)d_in[0];
  const int*   eidx   = (const int*)d_in[1];
  const float* eattr  = (const float*)d_in[2];
  const int*   batch  = (const int*)d_in[3];
  const float* W_emb  = (const float*)d_in[4];
  const float* b_emb  = (const float*)d_in[5];
  const float* Wc     = (const float*)d_in[6];
  const float* bc     = (const float*)d_in[7];
  const float* gamma  = (const float*)d_in[8];
  const float* beta   = (const float*)d_in[9];
  const float* Wh     = (const float*)d_in[10];
  const float* bh     = (const float*)d_in[11];
  const float* Wout   = (const float*)d_in[12];
  const float* bout   = (const float*)d_in[13];
  float* out = (float*)d_out;

  const int N  = in_sizes[3];
  const int E  = in_sizes[1] / 2;
  const int Fn = in_sizes[0] / N;      // 92
  const int H  = in_sizes[5];          // 128
  const int L  = in_sizes[7] / H;      // 3
  const int Kc = H + in_sizes[2] / E;  // 192
  const int Kp = 96;                   // padded embedding K

  const int* rows = eidx;
  const int* cols = eidx + E;

  char* ws = (char*)d_ws;
  size_t off = 0;
  auto alloc = [&](size_t bytes) { void* p = ws + off; off += (bytes + 255) / 256 * 256; return p; };
  float*           h        = (float*)alloc((size_t)N * 128 * 4);
  __hip_bfloat16*  hb       = (__hip_bfloat16*)alloc((size_t)N * 128 * 2);
  __hip_bfloat16*  STb      = (__hip_bfloat16*)alloc((size_t)N * Kc * 2);
  __hip_bfloat16*  xb       = (__hip_bfloat16*)alloc((size_t)N * Kp * 2);
  __hip_bfloat16*  Wet      = (__hip_bfloat16*)alloc((size_t)H * Kp * 2);
  __hip_bfloat16*  Wct      = (__hip_bfloat16*)alloc((size_t)L * H * Kc * 2);
  float*           deg      = (float*)alloc((size_t)N * 4);
  int*             row_ptr  = (int*)alloc((size_t)(N + 1) * 4);
  int*             cnt      = (int*)alloc((size_t)N * 4 * 2);
  int*             fill_cnt = cnt + N;
  int*             csr_col  = (int*)alloc((size_t)E * 4);
  int*             csr_eid  = (int*)alloc((size_t)E * 4);
  (void)ws_size; (void)n_in;

  const int prep_total = N * Kp + H * Kp + L * H * Kc;
  prep_all<<<dim3((prep_total + 255) / 256), 256, 0, stream>>>(
      x, xb, W_emb, Wet, Wc, Wct, cnt, N, Fn, Kp, H, L, Kc, prep_total);

  // CSR
  hist_kernel<<<dim3((E + 255) / 256), 256, 0, stream>>>(rows, cnt, E);
  scan_kernel<<<dim3(1), 1024, 0, stream>>>(cnt, row_ptr, N);
  fill_kernel<<<dim3((E + 255) / 256), 256, 0, stream>>>(rows, cols, row_ptr, fill_cnt,
                                                         csr_col, csr_eid, E);
  // T (layer-invariant, bf16) + deg
  build_T_deg<<<dim3((N + 3) / 4), 256, 0, stream>>>(eattr, row_ptr, csr_eid, STb, deg, N);

  // embedding: h = relu(xb @ Wet^T + b_emb), hb = bf16(h)
  gemm_mfma<0, 96><<<dim3((N + 63) / 64), 256, 0, stream>>>(
      xb, Wet, b_emb, nullptr, nullptr, nullptr, nullptr, h, hb, N);

  // conv layers
  for (int l = 0; l < L; l++) {
    scatter_S<<<dim3((N + 3) / 4), 256, 0, stream>>>(hb, row_ptr, csr_col, STb, N);
    gemm_mfma<1, 192><<<dim3((N + 63) / 64), 256, 0, stream>>>(
        STb, Wct + (size_t)l * H * Kc, nullptr, deg,
        bc + (size_t)l * H, gamma + (size_t)l * H, beta + (size_t)l * H, h, hb, N);
  }

  // pool + head
  pool_head<<<dim3(out_size), 128, 0, stream>>>(h, batch, Wh, bh, Wout, bout, out, N);
}